// Round 10
// baseline (269.985 us; speedup 1.0000x reference)
//
#include <hip/hip_runtime.h>
#include <stdint.h>

// S6Layer on MI355X — R10: FULLY FUSED single kernel.
// R1-R9 evidence: every unfused GEMM structure (LDS dbuf, pinned DMA, reg
// pipelines, 2-4 blocks/CU) lands at 62-98 us with MfmaUtil 5-8% — a floor
// no per-kernel knob moves. Fusion removes ~150MB intermediate traffic and 4
// of 6 dispatches. Tile = 32 tokens = one scan chunk (state resets per 32).
// Per block: LN -> G1(dtin) -> G2+softplus -> G1(xp) -> scan -> G1(z)+gate
// -> G3+residual. A-operands in LDS (66KB -> 2 blocks/CU); weights (1.1MB,
// L2-resident) streamed as B-fragments direct from global (barrier-free).
#define B_  8
#define L_  4096
#define DM  256
#define DI  384
#define DS  8
#define M_  (B_*L_)   // 32768 tokens

typedef float f32x4 __attribute__((ext_vector_type(4)));
typedef short s16x8 __attribute__((ext_vector_type(8)));

__device__ __forceinline__ unsigned short f2bf(float f) {
  union { float f; uint32_t u; } v; v.f = f;
  uint32_t r = v.u + 0x7FFFu + ((v.u >> 16) & 1u);   // RNE
  return (unsigned short)(r >> 16);
}
__device__ __forceinline__ float bf2f(unsigned short h) {
  union { uint32_t u; float f; } v; v.u = ((uint32_t)h) << 16;
  return v.f;
}
__device__ __forceinline__ float silu_f(float x) { return x / (1.f + __expf(-x)); }

// ---------------- weight fp32 -> bf16 ----------------
__global__ __launch_bounds__(256) void cvt_kernel(
    const float* __restrict__ w0, const float* __restrict__ w1, const float* __restrict__ w2,
    unsigned short* __restrict__ o0, unsigned short* __restrict__ o1, unsigned short* __restrict__ o2) {
  int i = blockIdx.x * 256 + threadIdx.x;
  if (i < 3*DI*DM) o0[i] = f2bf(w0[i]);
  if (i < DI*DI)   o1[i] = f2bf(w1[i]);
  if (i < DM*DI)   o2[i] = f2bf(w2[i]);
}

// ---- one GEMM phase: acc[2][NI] += sA(32 x 32*KS, stride ASTR) @ W^T ----
// A-frag: lane(fr,fq) reads sA[row=mi*16+fr][ks*32+fq*8 ..+8] (b128).
// B-frag: W row (nbase+ni*16+fr), 16B at ks*32+fq*8 — direct from global
// (L2-hot, no barrier dependency -> compiler may hoist/overlap freely).
template<int NI, int KS>
__device__ __forceinline__ void mm_phase(
    const unsigned short* __restrict__ sA, int ASTR,
    const unsigned short* __restrict__ W, int WSTR, int nbase,
    int fr, int fq, f32x4 acc[2][NI])
{
  #pragma unroll
  for (int mi = 0; mi < 2; ++mi)
    #pragma unroll
    for (int ni = 0; ni < NI; ++ni) acc[mi][ni] = (f32x4){0.f, 0.f, 0.f, 0.f};
  #pragma unroll
  for (int ks = 0; ks < KS; ++ks) {
    s16x8 af[2], bf[NI];
    #pragma unroll
    for (int mi = 0; mi < 2; ++mi)
      af[mi] = *(const s16x8*)(sA + (mi*16 + fr)*ASTR + ks*32 + fq*8);
    #pragma unroll
    for (int ni = 0; ni < NI; ++ni)
      bf[ni] = *(const s16x8*)(W + (size_t)(nbase + ni*16 + fr)*WSTR + ks*32 + fq*8);
    #pragma unroll
    for (int mi = 0; mi < 2; ++mi)
      #pragma unroll
      for (int ni = 0; ni < NI; ++ni)
        acc[mi][ni] = __builtin_amdgcn_mfma_f32_16x16x32_bf16(af[mi], bf[ni], acc[mi][ni], 0, 0, 0);
  }
}

// ---------------- the fused layer kernel ----------------
// block = 32 tokens (1 scan chunk), 256 thr (4 waves). Wave w owns output
// cols [w*96, w*96+96) for DI-wide stages, [w*64, ..) for the DM-wide G3.
// LDS: sXN 32x264 (pad: LN writes conflict-free, frag reads ~2-way),
//      sDT 32x392 (dtin -> dt -> y in place), sXP 32x392 (xp -> yz in place).
__global__ __launch_bounds__(256, 2) void fused_s6(
    const float* __restrict__ x, const float* __restrict__ gamma, const float* __restrict__ beta,
    const unsigned short* __restrict__ Win, const float* __restrict__ b_in,
    const unsigned short* __restrict__ Wdt, const float* __restrict__ b_dt,
    const float* __restrict__ A_log, const float* __restrict__ D_vec,
    const unsigned short* __restrict__ Wout, const float* __restrict__ b_out,
    float* __restrict__ out)
{
  __shared__ unsigned short sXN[32*264];
  __shared__ unsigned short sDT[32*392];
  __shared__ unsigned short sXP[32*392];

  const int t    = threadIdx.x;
  const int lane = t & 63;
  const int w    = t >> 6;
  const int fr   = lane & 15;
  const int fq   = lane >> 4;
  const int m0   = blockIdx.x * 32;

  // ---- P0: LayerNorm. Wave w handles rows {w+4i}; lane covers cols l*4..+3
  {
    const float4 g  = *(const float4*)(gamma + lane*4);
    const float4 bb = *(const float4*)(beta  + lane*4);
    const float* xt = x + (size_t)m0 * DM;
    #pragma unroll
    for (int i = 0; i < 8; ++i) {
      int row = w + i*4;
      const float4 v = *(const float4*)(xt + row*DM + lane*4);
      float s  = v.x + v.y + v.z + v.w;
      float ss = v.x*v.x + v.y*v.y + v.z*v.z + v.w*v.w;
      #pragma unroll
      for (int off = 32; off > 0; off >>= 1) {
        s  += __shfl_xor(s,  off, 64);
        ss += __shfl_xor(ss, off, 64);
      }
      float mean = s * (1.f/DM);
      float rstd = rsqrtf(ss * (1.f/DM) - mean*mean + 1e-5f);
      ushort4 o;
      o.x = f2bf((v.x - mean)*rstd*g.x + bb.x);
      o.y = f2bf((v.y - mean)*rstd*g.y + bb.y);
      o.z = f2bf((v.z - mean)*rstd*g.z + bb.z);
      o.w = f2bf((v.w - mean)*rstd*g.w + bb.w);
      *(ushort4*)(sXN + row*264 + lane*4) = o;
    }
  }
  __syncthreads();

  // ---- P1: dtin panel: sDT = sXN @ Win[768+..]^T + b_in  (no activation)
  {
    f32x4 acc[2][6];
    mm_phase<6, 8>(sXN, 264, Win, DM, 768 + w*96, fr, fq, acc);
    #pragma unroll
    for (int ni = 0; ni < 6; ++ni) {
      int col = w*96 + ni*16 + fr;
      float bv = b_in[768 + col];
      #pragma unroll
      for (int mi = 0; mi < 2; ++mi)
        #pragma unroll
        for (int r = 0; r < 4; ++r)
          sDT[(mi*16 + fq*4 + r)*392 + col] = f2bf(acc[mi][ni][r] + bv);
    }
  }
  __syncthreads();

  // ---- P2: dt = softplus(sDT @ Wdt^T + b_dt), in place
  {
    f32x4 acc[2][6];
    mm_phase<6, 12>(sDT, 392, Wdt, DI, w*96, fr, fq, acc);
    __syncthreads();               // all waves done READING sDT
    #pragma unroll
    for (int ni = 0; ni < 6; ++ni) {
      int col = w*96 + ni*16 + fr;
      float bv = b_dt[col];
      #pragma unroll
      for (int mi = 0; mi < 2; ++mi)
        #pragma unroll
        for (int r = 0; r < 4; ++r) {
          float c = acc[mi][ni][r] + bv;
          float sp = (c > 20.f) ? c : log1pf(__expf(c));
          sDT[(mi*16 + fq*4 + r)*392 + col] = f2bf(sp);
        }
    }
  }

  // ---- P3: xp panel: sXP = silu(sXN @ Win[0..]^T + b_in)
  {
    f32x4 acc[2][6];
    mm_phase<6, 8>(sXN, 264, Win, DM, w*96, fr, fq, acc);
    #pragma unroll
    for (int ni = 0; ni < 6; ++ni) {
      int col = w*96 + ni*16 + fr;
      float bv = b_in[col];
      #pragma unroll
      for (int mi = 0; mi < 2; ++mi)
        #pragma unroll
        for (int r = 0; r < 4; ++r)
          sXP[(mi*16 + fq*4 + r)*392 + col] = f2bf(silu_f(acc[mi][ni][r] + bv));
    }
  }
  __syncthreads();                 // sDT(dt) + sXP(xp) ready for scan

  // ---- P4: scan over 32 steps; y overwrites dt in sDT (same (tt,ch) owner)
  for (int ch = t; ch < DI; ch += 256) {
    float a[DS];
    const float4 al0 = *(const float4*)(A_log + ch*DS);
    const float4 al1 = *(const float4*)(A_log + ch*DS + 4);
    a[0] = -__expf(al0.x); a[1] = -__expf(al0.y); a[2] = -__expf(al0.z); a[3] = -__expf(al0.w);
    a[4] = -__expf(al1.x); a[5] = -__expf(al1.y); a[6] = -__expf(al1.z); a[7] = -__expf(al1.w);
    float h[DS] = {0.f,0.f,0.f,0.f,0.f,0.f,0.f,0.f};
    #pragma unroll 4
    for (int tt = 0; tt < 32; ++tt) {
      float dtv = bf2f(sDT[tt*392 + ch]);
      float xv  = bf2f(sXP[tt*392 + ch]);
      float y = 0.f;
      #pragma unroll
      for (int s = 0; s < DS; ++s) {
        h[s] = h[s] * __expf(dtv * a[s]) + xv;
        y += h[s];
      }
      sDT[tt*392 + ch] = f2bf(y);
    }
  }
  __syncthreads();                 // sDT now holds y

  // ---- P5: z panel + gating: yz = y*silu(z) + xp*D, overwrites sXP
  {
    f32x4 acc[2][6];
    mm_phase<6, 8>(sXN, 264, Win, DM, 384 + w*96, fr, fq, acc);
    #pragma unroll
    for (int ni = 0; ni < 6; ++ni) {
      int col = w*96 + ni*16 + fr;
      float bv = b_in[384 + col];
      float Dv = D_vec[col];
      #pragma unroll
      for (int mi = 0; mi < 2; ++mi)
        #pragma unroll
        for (int r = 0; r < 4; ++r) {
          int row = mi*16 + fq*4 + r;
          float zv  = silu_f(acc[mi][ni][r] + bv);
          float yv  = bf2f(sDT[row*392 + col]);
          float xpv = bf2f(sXP[row*392 + col]);
          sXP[row*392 + col] = f2bf(yv * zv + xpv * Dv);
        }
    }
  }
  __syncthreads();                 // sXP now holds yz

  // ---- P6: out = sXP(yz) @ Wout^T + b_out + residual(x)
  {
    f32x4 acc[2][4];
    mm_phase<4, 12>(sXP, 392, Wout, DI, w*64, fr, fq, acc);
    #pragma unroll
    for (int ni = 0; ni < 4; ++ni) {
      int gn = w*64 + ni*16 + fr;
      float bv = b_out[gn];
      #pragma unroll
      for (int mi = 0; mi < 2; ++mi)
        #pragma unroll
        for (int r = 0; r < 4; ++r) {
          size_t gm = (size_t)(m0 + mi*16 + fq*4 + r);
          out[gm*DM + gn] = acc[mi][ni][r] + bv + x[gm*DM + gn];
        }
    }
  }
}

extern "C" void kernel_launch(void* const* d_in, const int* in_sizes, int n_in,
                              void* d_out, int out_size, void* d_ws, size_t ws_size,
                              hipStream_t stream) {
  const float* x     = (const float*)d_in[0];
  const float* gamma = (const float*)d_in[1];
  const float* beta  = (const float*)d_in[2];
  const float* W_in  = (const float*)d_in[3];
  const float* b_in  = (const float*)d_in[4];
  const float* W_dt  = (const float*)d_in[5];
  const float* b_dt  = (const float*)d_in[6];
  const float* A_log = (const float*)d_in[7];
  const float* D_vec = (const float*)d_in[8];
  const float* W_out = (const float*)d_in[9];
  const float* b_out = (const float*)d_in[10];
  float* out = (float*)d_out;

  char* ws = (char*)d_ws;
  unsigned short* winb  = (unsigned short*)ws;                       // 3*DI*DM
  unsigned short* wdtb  = winb + (size_t)3*DI*DM;                    // DI*DI
  unsigned short* woutb = wdtb + (size_t)DI*DI;                      // DM*DI

  cvt_kernel<<<dim3((3*DI*DM + 255)/256), 256, 0, stream>>>(
      W_in, W_dt, W_out, winb, wdtb, woutb);
  fused_s6<<<dim3(M_/32), 256, 0, stream>>>(
      x, gamma, beta, winb, b_in, wdtb, b_dt, A_log, D_vec, woutb, b_out, out);
}